// Round 15
// baseline (270.589 us; speedup 1.0000x reference)
//
#include <hip/hip_runtime.h>

// MDTA: B=4, C=384, H=W=128, HEADS=8, D=48
#define HW    16384
#define WD    128
#define CCH   384
#define NB    4
#define NHEAD 8
#define DH    48
#define NCHUNK 16  // score partial chunks (pixels per chunk = HW/NCHUNK = 1024)
#define PREPB 889  // prep blocks appended to ln grid (455040 elems / 512)

typedef unsigned short u16;
typedef unsigned int   u32;
typedef __bf16 bf16x8 __attribute__((ext_vector_type(8)));
typedef float  f32x4  __attribute__((ext_vector_type(4)));

__device__ __forceinline__ float bf2f(u16 u){ u32 t=((u32)u)<<16; float f; __builtin_memcpy(&f,&t,4); return f; }
__device__ __forceinline__ u16 f2bf(float f){ u32 x; __builtin_memcpy(&x,&f,4); u32 r=x+0x7fffu+((x>>16)&1u); return (u16)(r>>16); }
__device__ __forceinline__ f32x4 zero4(){ f32x4 z = {0.f,0.f,0.f,0.f}; return z; }

#define GL16(g,l) __builtin_amdgcn_global_load_lds(\
    (const __attribute__((address_space(1))) void*)(g), \
    (__attribute__((address_space(3))) void*)(l), 16, 0, 0)

// ---------------- LayerNorm (-> xn_t [b][p][c]) + weight prep, one launch ----------------
__global__ __launch_bounds__(512, 4) void ln_prep_kernel(
    const float* __restrict__ x, const float* __restrict__ gamma,
    const float* __restrict__ beta, u16* __restrict__ xnt,
    const float* wq_p, const float* wk_p, const float* wv_p,
    const float* bq_p, const float* bk_p, const float* bv_p,
    const float* wq_d, const float* wk_d, const float* wv_d,
    const float* bq_d, const float* bk_d, const float* bv_d,
    u16* Wqkv, float* bias_p, float* wdc, float* bdc)
{
    if (blockIdx.x >= 256) {
        if (blockIdx.y != 0) return;
        int idx = (blockIdx.x - 256)*512 + threadIdx.x;
        const int NW = 3*CCH*CCH;                 // 442368
        if (idx < NW) {
            int m = idx / CCH, c = idx % CCH;
            int w = m / CCH, o = m % CCH;
            const float* src = (w==0)? wq_p : (w==1)? wk_p : wv_p;
            Wqkv[idx] = f2bf(src[o*CCH + c]);
        } else if (idx < NW + 3*CCH) {
            int m = idx - NW; int w = m/CCH, o = m%CCH;
            const float* src = (w==0)? bq_p : (w==1)? bk_p : bv_p;
            bias_p[m] = src[o];
        } else if (idx < NW + 3*CCH + 3*CCH*9) {
            int r = idx - NW - 3*CCH; int m = r/9, k = r%9;
            int w = m/CCH, o = m%CCH;
            const float* src = (w==0)? wq_d : (w==1)? wk_d : wv_d;
            wdc[r] = src[o*9 + k];
        } else if (idx < NW + 3*CCH + 3*CCH*9 + 3*CCH) {
            int m = idx - NW - 3*CCH - 3*CCH*9; int w = m/CCH, o = m%CCH;
            const float* src = (w==0)? bq_d : (w==1)? bk_d : bv_d;
            bdc[m] = src[o];
        }
        return;
    }
    __shared__ __align__(16) char lds[32*392*2 + 512];
    u16  (*tile)[392] = (u16(*)[392])lds;
    f32x4* redS  = (f32x4*)lds;                // overlays tile (temporally disjoint)
    f32x4* redS2 = (f32x4*)(lds + 8192);
    float* mu_s  = (float*)(lds + 32*392*2);
    float* rs_s  = mu_s + 64;
    int b  = blockIdx.y;
    int p0 = blockIdx.x*64;
    int t  = threadIdx.x;
    int tx = t & 15, cg = t >> 4;              // 16 pixel-quads x 32 channel-groups of 12
    const float* xb = x + (size_t)b*CCH*HW + p0 + tx*4;
    f32x4 vals[12];
    f32x4 s = zero4(), s2 = zero4();
    #pragma unroll
    for (int cc = 0; cc < 12; ++cc) {
        f32x4 v = *(const f32x4*)(xb + (size_t)(cg*12+cc)*HW);
        vals[cc] = v;
        s += v; s2 += v*v;
    }
    redS[cg*16+tx] = s; redS2[cg*16+tx] = s2;
    __syncthreads();
    if (t < 64) {
        int q = t >> 2, comp = t & 3;
        const float* rs1 = (const float*)redS;
        const float* rs2 = (const float*)redS2;
        float st = 0.f, st2 = 0.f;
        #pragma unroll
        for (int g2 = 0; g2 < 32; ++g2) {
            st  += rs1[(g2*16+q)*4 + comp];
            st2 += rs2[(g2*16+q)*4 + comp];
        }
        float mu  = st*(1.f/CCH);
        float var = st2*(1.f/CCH) - mu*mu;
        mu_s[t] = mu;
        rs_s[t] = rsqrtf(var + 1e-5f);
    }
    __syncthreads();
    f32x4 mu4, rs4;
    #pragma unroll
    for (int j = 0; j < 4; ++j) { mu4[j] = mu_s[tx*4+j]; rs4[j] = rs_s[tx*4+j]; }
    u32 pk[12][2];
    #pragma unroll
    for (int cc = 0; cc < 12; ++cc) {
        int c = cg*12 + cc;
        float gm = gamma[c], bt = beta[c];
        f32x4 v = (vals[cc] - mu4) * rs4;
        u16 o0 = f2bf(v[0]*gm + bt), o1 = f2bf(v[1]*gm + bt);
        u16 o2 = f2bf(v[2]*gm + bt), o3 = f2bf(v[3]*gm + bt);
        pk[cc][0] = (u32)o0 | ((u32)o1 << 16);
        pk[cc][1] = (u32)o2 | ((u32)o3 << 16);
    }
    u16* xto = xnt + (size_t)b*CCH*HW;
    int half = tx >> 3, txl = tx & 7;
    #pragma unroll
    for (int p2 = 0; p2 < 2; ++p2) {
        if (half == p2) {
            #pragma unroll
            for (int i = 0; i < 4; ++i) {       // pixel within quad
                int row = txl*4 + i;
                #pragma unroll
                for (int j = 0; j < 3; ++j) {   // 4-channel group
                    #define EXTB(cc) ((pk[cc][i>>1] >> (16*(i&1))) & 0xffffu)
                    u32 a0 = EXTB(4*j+0) | (EXTB(4*j+1) << 16);
                    u32 a1 = EXTB(4*j+2) | (EXTB(4*j+3) << 16);
                    #undef EXTB
                    uint2 pr; pr.x = a0; pr.y = a1;
                    *(uint2*)&tile[row][cg*12 + j*4] = pr;
                }
            }
        }
        __syncthreads();
        #pragma unroll
        for (int k = 0; k < 3; ++k) {
            int idx = t + k*512;
            int p = idx / 48, q = idx % 48;
            *(uint4*)(xto + (size_t)(p0 + p2*32 + p)*CCH + q*8) = *(const uint4*)&tile[p][q*8];
        }
        __syncthreads();
    }
}

// ---------------- NT MFMA GEMM: C[m][n] = sum_k A[m][k]*B[n][k]  (K=384) ----------------
// 128x128 tile, BK=64, 8 waves (64x32 each). XCD-aware block swizzle (T1).
// TRANSB=0: single-buffer 32KB, GL16 both operands (r3-proven structure).
// TRANSB=1: B=[k][n] (V in [c][p]). Full dbuf + raw s_barrier + counted vmcnt.
// EPI 0: +bias, bf16 store via LDS shuffle -> 256B contiguous segments.
// EPI 1: +bias + residual from xn_t [p][c] via LDS transpose tile, f32x4 store.
template<int EPI, int TRANSB>
__global__ __launch_bounds__(512) void gemm_nt(
    const u16* __restrict__ A, const u16* __restrict__ Bm, void* __restrict__ Cout,
    const float* __restrict__ bias, const u16* __restrict__ xnadd,
    long A_bstride, long B_bstride, long C_bstride)
{
    constexpr int SMBYTES = TRANSB ? 65536 : 32768;
    __shared__ __align__(16) char smraw[SMBYTES];
    u16* smA = (u16*)smraw;                               // TRANSB=1: 2 x 16KB dbuf
    u16* smB = (u16*)(smraw + (TRANSB ? 32768 : 16384));  // TRANSB=1: 2 x 16KB dbuf

    // XCD swizzle: lin -> (lin%8)*(N/8) + lin/8 (bijective when N%8==0)
    int gx = gridDim.x, gy = gridDim.y;
    int Ngrid = gx*gy*gridDim.z;
    int lin = blockIdx.x + gx*(blockIdx.y + gy*blockIdx.z);
    int swz = ((Ngrid & 7) == 0) ? ((lin & 7)*(Ngrid >> 3) + (lin >> 3)) : lin;
    int bx = swz % gx; int rem = swz / gx;
    int by = rem % gy; int b  = rem / gy;
    int m0 = bx*128, n0 = by*128;

    const u16* Ab = A  + (size_t)b*A_bstride;
    const u16* Bb = Bm + (size_t)b*B_bstride;
    int t = threadIdx.x;
    int lane = t & 63, w = t >> 6;
    int wr = w >> 2, wc = w & 3;              // rows wr*64.., cols wc*32..
    int l15 = lane & 15, g = lane >> 4;
    int s7 = l15 & 7;

    int rowA[2], kksA[2];
    #pragma unroll
    for (int r = 0; r < 2; ++r) {
        int e = (r*512 + t)*8;
        rowA[r] = e >> 6;
        int kk  = e & 63;
        kksA[r] = kk ^ ((rowA[r]&7)<<3);      // pre-swizzle source -> linear LDS dest is swizzled
    }
    // TRANSB=1 reg-staging coords: thread owns channels (cB, cB+1) x 8 pixels
    int cB  = (2*t) & 63;                     // even
    int pxg = (2*t) >> 6;                     // 0..15

    f32x4 acc[4][2];
    #pragma unroll
    for (int i=0;i<4;++i) { acc[i][0] = zero4(); acc[i][1] = zero4(); }

#define COMPUTE(sAp, sBp) { \
    const u16* sA_ = (sAp); const u16* sB_ = (sBp); \
    _Pragma("unroll") \
    for (int kh = 0; kh < 2; ++kh) { \
        int u = (kh*4 + g) ^ s7; \
        bf16x8 af[4], bq[2]; \
        _Pragma("unroll") \
        for (int mi=0;mi<4;++mi) { \
            int row = wr*64 + mi*16 + l15; \
            af[mi] = *(const bf16x8*)&sA_[row*64 + u*8]; \
        } \
        _Pragma("unroll") \
        for (int nj=0;nj<2;++nj) { \
            int row = wc*32 + nj*16 + l15; \
            bq[nj] = *(const bf16x8*)&sB_[row*64 + u*8]; \
        } \
        _Pragma("unroll") \
        for (int mi=0;mi<4;++mi) \
            _Pragma("unroll") \
            for (int nj=0;nj<2;++nj) \
                acc[mi][nj] = __builtin_amdgcn_mfma_f32_16x16x32_bf16(af[mi], bq[nj], acc[mi][nj], 0,0,0); \
    } }

#define WRITE_SMB(dst, va, vb) { \
    u16 e0[8], e1[8]; \
    __builtin_memcpy(e0,&(va),16); __builtin_memcpy(e1,&(vb),16); \
    _Pragma("unroll") \
    for (int j=0;j<8;++j) { \
        u32 wv = (u32)e0[j] | ((u32)e1[j]<<16); \
        *(u32*)((dst) + (pxg*8+j)*64 + (cB ^ (j<<3))) = wv; \
    } }

    if (!TRANSB) {
        // ---- r3-proven single-buffer 2-barrier loop ----
        #pragma unroll
        for (int r = 0; r < 2; ++r) {
            GL16(Ab + (size_t)(m0+rowA[r])*CCH + kksA[r], smA + r*4096 + w*512);
            GL16(Bb + (size_t)(n0+rowA[r])*CCH + kksA[r], smB + r*4096 + w*512);
        }
        __syncthreads();
        for (int ks = 0; ks < 6; ++ks) {
            COMPUTE(smA, smB);
            if (ks < 5) {
                __syncthreads();
                int k1 = (ks+1)*64;
                #pragma unroll
                for (int r = 0; r < 2; ++r) {
                    GL16(Ab + (size_t)(m0+rowA[r])*CCH + k1 + kksA[r], smA + r*4096 + w*512);
                    GL16(Bb + (size_t)(n0+rowA[r])*CCH + k1 + kksA[r], smB + r*4096 + w*512);
                }
                __syncthreads();
            }
        }
    } else {
        // ---- pipelined: dbuf + raw barrier + counted vmcnt; B 2-deep in regs ----
        uint4 s0a, s0b, s1a, s1b;
        s0a = *(const uint4*)(Bb + (size_t)cB*HW     + n0 + pxg*8);
        s0b = *(const uint4*)(Bb + (size_t)(cB+1)*HW + n0 + pxg*8);
        #pragma unroll
        for (int r = 0; r < 2; ++r)
            GL16(Ab + (size_t)(m0+rowA[r])*CCH + kksA[r], smA + r*4096 + w*512);
        WRITE_SMB(smB, s0a, s0b);             // compiler auto-waits set0
        s1a = *(const uint4*)(Bb + (size_t)(64+cB)*HW   + n0 + pxg*8);   // B(k1) -> set1
        s1b = *(const uint4*)(Bb + (size_t)(64+cB+1)*HW + n0 + pxg*8);
        asm volatile("s_waitcnt vmcnt(2)" ::: "memory");   // A done; set1 stays in flight
        asm volatile("s_waitcnt lgkmcnt(0)" ::: "memory");
        __builtin_amdgcn_sched_barrier(0);
        __builtin_amdgcn_s_barrier();

        #pragma unroll
        for (int ks = 0; ks < 6; ++ks) {
            int cur = ks & 1, nxt = cur ^ 1;
            if (ks < 5) {                      // A for ks+1 (L2-hot wf_eff)
                int k1 = (ks+1)*64;
                #pragma unroll
                for (int r = 0; r < 2; ++r)
                    GL16(Ab + (size_t)(m0+rowA[r])*CCH + k1 + kksA[r],
                         smA + nxt*8192 + r*4096 + w*512);
            }
            if (ks < 4) {                      // B for ks+2 into the freed set
                int k2 = (ks+2)*64;
                if ((ks & 1) == 0) {
                    s0a = *(const uint4*)(Bb + (size_t)(k2+cB)*HW   + n0 + pxg*8);
                    s0b = *(const uint4*)(Bb + (size_t)(k2+cB+1)*HW + n0 + pxg*8);
                } else {
                    s1a = *(const uint4*)(Bb + (size_t)(k2+cB)*HW   + n0 + pxg*8);
                    s1b = *(const uint4*)(Bb + (size_t)(k2+cB+1)*HW + n0 + pxg*8);
                }
            }
            COMPUTE(smA + cur*8192, smB + cur*8192);
            if (ks < 5) {
                if (((ks+1) & 1) == 0) { WRITE_SMB(smB + nxt*8192, s0a, s0b); }
                else                   { WRITE_SMB(smB + nxt*8192, s1a, s1b); }
                if (ks < 4) asm volatile("s_waitcnt vmcnt(2)" ::: "memory");  // A drained, B(ks+2) in flight
                else        asm volatile("s_waitcnt vmcnt(0)" ::: "memory");
                asm volatile("s_waitcnt lgkmcnt(0)" ::: "memory");
                __builtin_amdgcn_sched_barrier(0);
                __builtin_amdgcn_s_barrier();
            }
        }
    }

    if (EPI == 0) {
        // LDS-shuffled bf16 epilogue: two halves of 64 rows; stores are 16B/lane,
        // 16 lanes = 256B contiguous segments (was 2B scalar stores = 32B segments).
        u16* ep16 = (u16*)smraw;              // [64][132] u16 = 16896 B per half
        #pragma unroll
        for (int half = 0; half < 2; ++half) {
            __syncthreads();                  // K-loop / prior half reads done
            if (wr == half) {
                #pragma unroll
                for (int mi=0;mi<4;++mi) {
                    #pragma unroll
                    for (int r=0;r<4;++r) {
                        int lrow = mi*16 + g*4 + r;
                        float bv = bias[m0 + half*64 + lrow];
                        #pragma unroll
                        for (int nj=0;nj<2;++nj)
                            ep16[lrow*132 + wc*32 + nj*16 + l15] = f2bf(acc[mi][nj][r] + bv);
                    }
                }
            }
            __syncthreads();
            #pragma unroll
            for (int k = 0; k < 2; ++k) {
                int idx = t + k*512;
                int lrow = idx >> 4, c8 = idx & 15;
                int grow = m0 + half*64 + lrow;
                int gcol = n0 + c8*8;
                uint4 v = *(const uint4*)&ep16[lrow*132 + c8*8];
                *(uint4*)((u16*)Cout + (size_t)b*C_bstride + (size_t)grow*HW + gcol) = v;
            }
        }
    } else {
        // LDS-shuffled epilogue + xn_t residual transpose tile.
        float* epi = (float*)smraw;                 // 64 x 132 f32 = 33792 B
        u16*   xt  = (u16*)(smraw + 33792);         // [64 ch][132 px] u16 = 16896 B
        const u16* xtg = xnadd + (size_t)b*CCH*HW;  // xn_t [p][c]
        #pragma unroll
        for (int half = 0; half < 2; ++half) {
            __syncthreads();                  // smraw free (K-loop / prior half done)
            // fill xt: 128 px x 64 ch of this half, transposed to [ch][px]
            #pragma unroll
            for (int q2 = 0; q2 < 2; ++q2) {
                int idx2 = t*2 + q2;          // 0..1023
                int px  = idx2 >> 3;          // 0..127
                int oct = idx2 & 7;           // 8 channel-octets
                int chl = (oct < 4) ? (half*32 + oct*8) : (64 + half*32 + (oct-4)*8);
                uint4 v4 = *(const uint4*)(xtg + (size_t)(n0+px)*CCH + m0 + chl);
                u16 e[8]; __builtin_memcpy(e, &v4, 16);
                int col = oct*8;              // lrow index 0..63
                #pragma unroll
                for (int j = 0; j < 8; ++j)
                    xt[(col+j)*132 + px] = e[j];
            }
            #pragma unroll
            for (int mi2 = 0; mi2 < 2; ++mi2) {
                int mi = half*2 + mi2;
                #pragma unroll
                for (int r = 0; r < 4; ++r) {
                    int lrow = wr*32 + mi2*16 + g*4 + r;
                    int grow = m0 + wr*64 + half*32 + mi2*16 + g*4 + r;
                    float bv = bias[grow];
                    #pragma unroll
                    for (int nj = 0; nj < 2; ++nj)
                        epi[lrow*132 + wc*32 + nj*16 + l15] = acc[mi][nj][r] + bv;
                }
            }
            __syncthreads();
            #pragma unroll
            for (int k = 0; k < 4; ++k) {
                int idx = t + k*512;
                int lrow = idx >> 5, cq = idx & 31;
                int grow = m0 + (lrow>>5)*64 + half*32 + (lrow&31);
                int gcol = n0 + cq*4;
                f32x4 v = *(const f32x4*)&epi[lrow*132 + cq*4];
                uint2 xv = *(const uint2*)&xt[lrow*132 + cq*4];   // 4 px bf16
                v[0] += bf2f((u16)xv.x);        v[1] += bf2f((u16)(xv.x>>16));
                v[2] += bf2f((u16)xv.y);        v[3] += bf2f((u16)(xv.y>>16));
                *(f32x4*)((float*)Cout + (size_t)b*C_bstride + (size_t)grow*HW + gcol) = v;
            }
        }
    }
#undef COMPUTE
#undef WRITE_SMB
}

// ---------------- depthwise 3x3 SAME, bf16 in/out, [b][cpb][p] ----------------
// LDS-staged: GL16 the 18-row halo tile (20 rows incl. pad) once per block;
// compute reads ds_read_b128 + LDS halos; y-boundary rows zeroed in LDS.
__global__ __launch_bounds__(256) void dw_kernel(
    const u16* __restrict__ in, u16* __restrict__ out,
    const float* __restrict__ wd, const float* __restrict__ bd, int cpb)
{
    __shared__ __align__(16) u16 srow[20*WD];     // 20 rows x 128 px bf16 = 5120 B
    int b  = blockIdx.z;
    int c  = blockIdx.y;
    int yt = blockIdx.x;                          // 0..7, 16 output rows each
    int t  = threadIdx.x;
    int lane = t & 63, w = t >> 6;
    int y0 = yt*16;
    const u16* plane = in + (size_t)b*cpb*HW + (size_t)c*HW;
    // stage rows r=0..15 (image y0-1+r, clamped), wave w -> LDS rows w*4..w*4+3
    {
        int r  = t >> 4;                          // 0..15
        int sg = t & 15;
        int yy = y0 - 1 + r;
        yy = yy < 0 ? 0 : (yy >= WD ? WD-1 : yy);
        GL16(plane + (size_t)yy*WD + sg*8, srow + w*4*WD);
    }
    if (t < 64) {                                 // rows 16..19 (17 used; 18,19 pad)
        int r  = 16 + (t >> 4);
        int sg = t & 15;
        int yy = y0 - 1 + r;
        yy = yy < 0 ? 0 : (yy >= WD ? WD-1 : yy);
        GL16(plane + (size_t)yy*WD + sg*8, srow + 16*WD);
    }
    __syncthreads();                              // drains vmcnt: tile resident
    if (yt == 0 && t < 16)
        ((uint4*)srow)[t] = make_uint4(0,0,0,0);              // image row -1 -> 0
    if (yt == (WD/16 - 1) && t < 16)
        *((uint4*)(srow + 17*WD) + t) = make_uint4(0,0,0,0);  // image row 128 -> 0
    __syncthreads();

    int ty = t >> 4, tx = t & 15;
    int y  = y0 + ty;
    int x0 = tx*8;
    float w9[9];
    #pragma unroll
    for (int i=0;i<9;++i) w9[i] = wd[c*9+i];
    float bv = bd[c];
    float rows[3][10];
    #pragma unroll
    for (int dy=0; dy<3; ++dy) {
        const u16* rp = srow + (ty+dy)*WD;
        rows[dy][0] = (tx==0) ? 0.f : bf2f(rp[x0-1]);
        uint4 v = *(const uint4*)(rp + x0);       // ds_read_b128, conflict-free
        u16 e[8]; __builtin_memcpy(e,&v,16);
        #pragma unroll
        for (int i=0;i<8;++i) rows[dy][1+i] = bf2f(e[i]);
        rows[dy][9] = (tx==15) ? 0.f : bf2f(rp[x0+8]);
    }
    u16 ovals[8];
    #pragma unroll
    for (int xo=0; xo<8; ++xo) {
        float a = bv;
        #pragma unroll
        for (int dy=0;dy<3;++dy)
            #pragma unroll
            for (int dx=0;dx<3;++dx)
                a += rows[dy][xo+dx] * w9[dy*3+dx];
        ovals[xo] = f2bf(a);
    }
    uint4 ov; __builtin_memcpy(&ov, ovals, 16);
    *(uint4*)(out + (size_t)b*cpb*HW + (size_t)c*HW + y*WD + x0) = ov;
}

// ---------------- scores partials: 4 waves split the pixel chunk, LDS cross-wave reduce ----------------
__global__ __launch_bounds__(256) void scores_kernel(const u16* __restrict__ Kp,
                                                     const u16* __restrict__ Qp,
                                                     float* __restrict__ S_part, int cpb)
{
    __shared__ float red[3*DH*DH];            // waves 1..3 partial dumps (27648 B)
    int pc = blockIdx.x;                      // 0..NCHUNK-1 pixel chunks
    int h  = blockIdx.y;
    int b  = blockIdx.z;
    int t  = threadIdx.x;
    int lane = t & 63, wv = t >> 6;
    int l15 = lane & 15, g = lane >> 4;
    const u16* Kb = Kp + (size_t)b*cpb*HW + (size_t)(h*DH)*HW;
    const u16* Qb = Qp + (size_t)b*cpb*HW + (size_t)(h*DH)*HW;
    int p0 = pc*(HW/NCHUNK) + wv*(HW/NCHUNK/4);    // 256 px per wave
    f32x4 acc[3][3];
    #pragma unroll
    for (int i=0;i<3;++i)
        #pragma unroll
        for (int j=0;j<3;++j) acc[i][j] = zero4();
    #pragma unroll
    for (int kk=0; kk<(HW/NCHUNK/4)/32; ++kk) {    // 8 iters
        int p = p0 + kk*32 + g*8;
        bf16x8 af[3], bq[3];
        #pragma unroll
        for (int it=0; it<3; ++it)
            af[it] = *(const bf16x8*)(Kb + (size_t)(it*16 + l15)*HW + p);
        #pragma unroll
        for (int jt=0; jt<3; ++jt)
            bq[jt] = *(const bf16x8*)(Qb + (size_t)(jt*16 + l15)*HW + p);
        #pragma unroll
        for (int it=0;it<3;++it)
            #pragma unroll
            for (int jt=0;jt<3;++jt)
                acc[it][jt] = __builtin_amdgcn_mfma_f32_16x16x32_bf16(af[it], bq[jt], acc[it][jt], 0,0,0);
    }
    if (wv > 0) {
        float* dst = red + (wv-1)*(DH*DH) + lane*36;
        #pragma unroll
        for (int it=0;it<3;++it)
            #pragma unroll
            for (int jt=0;jt<3;++jt)
                *(f32x4*)(dst + (it*3+jt)*4) = acc[it][jt];
    }
    __syncthreads();
    if (wv == 0) {
        #pragma unroll
        for (int it=0;it<3;++it)
            #pragma unroll
            for (int jt=0;jt<3;++jt) {
                #pragma unroll
                for (int w2=0; w2<3; ++w2)
                    acc[it][jt] += *(const f32x4*)(red + w2*(DH*DH) + lane*36 + (it*3+jt)*4);
            }
        float* Sp = S_part + ((size_t)pc*32 + b*NHEAD + h)*(DH*DH);
        #pragma unroll
        for (int it=0;it<3;++it)
            #pragma unroll
            for (int jt=0;jt<3;++jt)
                #pragma unroll
                for (int r=0;r<4;++r) {
                    int i = it*16 + g*4 + r;
                    int j = jt*16 + l15;
                    Sp[i*DH + j] = acc[it][jt][r];
                }
    }
}

// ---------------- fold (absorbs softmax): reduce partials + softmax + fold into wf ----------------
// wf_eff[b][o][n*48+i] = sum_j wf[o][n*48+j]*softmax(S)[b,n,i,j]
__global__ __launch_bounds__(256) void fold_kernel(const float* __restrict__ wf,
                                                   const float* __restrict__ S_part,
                                                   const float* __restrict__ alpha,
                                                   u16* __restrict__ wf_eff)
{
    __shared__ float softl[DH*DH];            // 9216 B
    __shared__ float wfl[16*DH];              // 3072 B
    int ob = blockIdx.x, h = blockIdx.y, b = blockIdx.z;
    int t = threadIdx.x;
    int bh = b*NHEAD + h;
    float ia = 1.f / alpha[h];
    for (int e = t; e < DH*DH; e += 256) {
        float s = 0.f;
        #pragma unroll
        for (int pc=0; pc<NCHUNK; ++pc) s += S_part[((size_t)pc*32 + bh)*(DH*DH) + e];
        softl[e] = s * ia;
    }
    for (int k = t; k < 16*DH; k += 256) {
        int ol = k / DH, j = k % DH;
        wfl[k] = wf[(size_t)(ob*16 + ol)*CCH + h*DH + j];
    }
    __syncthreads();
    if (t < DH) {
        float m = -1e30f;
        for (int j=0;j<DH;++j) m = fmaxf(m, softl[t*DH+j]);
        float sum = 0.f;
        for (int j=0;j<DH;++j) sum += __expf(softl[t*DH+j]-m);
        float inv = 1.f/sum;
        for (int j=0;j<DH;++j)
            softl[t*DH+j] = __expf(softl[t*DH+j]-m)*inv;
    }
    __syncthreads();
    #pragma unroll
    for (int r = 0; r < 3; ++r) {
        int out = r*256 + t;                  // 0..767
        int ol = out / DH, i = out % DH;
        const f32x4* wr_ = (const f32x4*)&wfl[ol*DH];
        const f32x4* sr  = (const f32x4*)&softl[i*DH];
        f32x4 a4 = zero4();
        #pragma unroll
        for (int j = 0; j < 12; ++j) a4 += wr_[j]*sr[j];
        float a = a4[0]+a4[1]+a4[2]+a4[3];
        wf_eff[((size_t)b*CCH + ob*16 + ol)*CCH + h*DH + i] = f2bf(a);
    }
}

extern "C" void kernel_launch(void* const* d_in, const int* in_sizes, int n_in,
                              void* d_out, int out_size, void* d_ws, size_t ws_size,
                              hipStream_t stream)
{
    const float* x    = (const float*)d_in[0];
    const float* ln_g = (const float*)d_in[1];
    const float* ln_b = (const float*)d_in[2];
    const float* wq_p = (const float*)d_in[3];
    const float* bq_p = (const float*)d_in[4];
    const float* wq_d = (const float*)d_in[5];
    const float* bq_d = (const float*)d_in[6];
    const float* wk_p = (const float*)d_in[7];
    const float* bk_p = (const float*)d_in[8];
    const float* wk_d = (const float*)d_in[9];
    const float* bk_d = (const float*)d_in[10];
    const float* wv_p = (const float*)d_in[11];
    const float* bv_p = (const float*)d_in[12];
    const float* wv_d = (const float*)d_in[13];
    const float* bv_d = (const float*)d_in[14];
    const float* alpha= (const float*)d_in[15];
    const float* wf   = (const float*)d_in[16];
    const float* bf_  = (const float*)d_in[17];

    char* ws = (char*)d_ws;
    size_t off = 0;
    auto alloc = [&](size_t bytes)->char* { char* p = ws + off; off += (bytes + 255) & ~(size_t)255; return p; };
    const size_t BIG  = (size_t)NB*CCH*HW*2;       // 50.3 MB bf16 [b][384][16384]
    const size_t BIG3 = 3*BIG;                     // 151 MB   [b][1152][16384]
    const size_t SMALLS = (size_t)3*CCH*CCH*2 + 3*CCH*4 + 3*CCH*9*4 + 3*CCH*4
                        + (size_t)NCHUNK*32*DH*DH*4 + (size_t)32*DH*DH*4
                        + (size_t)NB*CCH*CCH*2 + 16*256;
    const size_t NEED_FUSED = BIG + 2*BIG3 + SMALLS;
    const bool fused = (ws_size >= NEED_FUSED);
    const long BStr = (long)CCH*HW;

    if (fused) {
        u16* xn_t   = (u16*)alloc(BIG);
        u16* pwQKV  = (u16*)alloc(BIG3);
        u16* dwQKV  = (u16*)alloc(BIG3);
        u16*   Wqkv   = (u16*)  alloc((size_t)3*CCH*CCH*2);
        float* bias_p = (float*)alloc((size_t)3*CCH*4);
        float* wdc    = (float*)alloc((size_t)3*CCH*9*4);
        float* bdc    = (float*)alloc((size_t)3*CCH*4);
        float* S_part = (float*)alloc((size_t)NCHUNK*32*DH*DH*4);
        float* soft   = (float*)alloc((size_t)32*DH*DH*4);
        u16*   wf_eff = (u16*)  alloc((size_t)NB*CCH*CCH*2);
        (void)soft;

        ln_prep_kernel<<<dim3(256+PREPB,NB), 512, 0, stream>>>(
            x, ln_g, ln_b, xn_t,
            wq_p,wk_p,wv_p, bq_p,bk_p,bv_p, wq_d,wk_d,wv_d, bq_d,bk_d,bv_d,
            Wqkv, bias_p, wdc, bdc);
        // fused QKV pointwise: M=1152
        gemm_nt<0,0><<<dim3(9,128,NB), 512, 0, stream>>>(Wqkv, xn_t, pwQKV, bias_p, nullptr,
                                                         0, BStr, (long)3*CCH*HW);
        dw_kernel<<<dim3(8,3*CCH,NB), 256, 0, stream>>>(pwQKV, dwQKV, wdc, bdc, 3*CCH);
        scores_kernel<<<dim3(NCHUNK,NHEAD,NB), 256, 0, stream>>>(dwQKV + (size_t)CCH*HW, // K
                                                                 dwQKV,                  // Q
                                                                 S_part, 3*CCH);
        fold_kernel<<<dim3(CCH/16, NHEAD, NB), 256, 0, stream>>>(wf, S_part, alpha, wf_eff);
        // final: x_cap = wf_eff x V + bf + xn(from xn_t) ; V consumed directly in [c][p]
        gemm_nt<1,1><<<dim3(3,128,NB), 512, 0, stream>>>(wf_eff, dwQKV + (size_t)2*CCH*HW,
                                                         d_out, bf_, xn_t,
                                                         (long)CCH*CCH, (long)3*CCH*HW, BStr);
    } else {
        u16* xn_t  = (u16*)alloc(BIG);
        u16* pwA   = (u16*)alloc(BIG);
        u16* dwQ   = (u16*)alloc(BIG);
        u16* dwK   = (u16*)alloc(BIG);
        u16*   Wqkv   = (u16*)  alloc((size_t)3*CCH*CCH*2);
        float* bias_p = (float*)alloc((size_t)3*CCH*4);
        float* wdc    = (float*)alloc((size_t)3*CCH*9*4);
        float* bdc    = (float*)alloc((size_t)3*CCH*4);
        float* S_part = (float*)alloc((size_t)NCHUNK*32*DH*DH*4);
        float* soft   = (float*)alloc((size_t)32*DH*DH*4);
        u16*   wf_eff = (u16*)  alloc((size_t)NB*CCH*CCH*2);
        if (off > ws_size) return;
        (void)soft;
        u16* dwV = dwQ;                        // dwQ dead after scores

        ln_prep_kernel<<<dim3(256+PREPB,NB), 512, 0, stream>>>(
            x, ln_g, ln_b, xn_t,
            wq_p,wk_p,wv_p, bq_p,bk_p,bv_p, wq_d,wk_d,wv_d, bq_d,bk_d,bv_d,
            Wqkv, bias_p, wdc, bdc);
        gemm_nt<0,0><<<dim3(3,128,NB), 512, 0, stream>>>(Wqkv,           xn_t, pwA, bias_p,       nullptr, 0, BStr, BStr);
        dw_kernel<<<dim3(8,CCH,NB), 256, 0, stream>>>(pwA, dwQ, wdc,         bdc,       CCH);
        gemm_nt<0,0><<<dim3(3,128,NB), 512, 0, stream>>>(Wqkv + CCH*CCH, xn_t, pwA, bias_p + CCH, nullptr, 0, BStr, BStr);
        dw_kernel<<<dim3(8,CCH,NB), 256, 0, stream>>>(pwA, dwK, wdc + CCH*9, bdc + CCH, CCH);
        scores_kernel<<<dim3(NCHUNK,NHEAD,NB), 256, 0, stream>>>(dwK, dwQ, S_part, CCH);
        fold_kernel<<<dim3(CCH/16, NHEAD, NB), 256, 0, stream>>>(wf, S_part, alpha, wf_eff);
        gemm_nt<0,0><<<dim3(3,128,NB), 512, 0, stream>>>(Wqkv + 2*CCH*CCH, xn_t, pwA, bias_p + 2*CCH, nullptr, 0, BStr, BStr);
        dw_kernel<<<dim3(8,CCH,NB), 256, 0, stream>>>(pwA, dwV, wdc + 2*CCH*9, bdc + 2*CCH, CCH);
        gemm_nt<1,1><<<dim3(3,128,NB), 512, 0, stream>>>(wf_eff, dwV, d_out, bf_, xn_t,
                                                         (long)CCH*CCH, BStr, BStr);
    }
}

// Round 16
// 262.892 us; speedup vs baseline: 1.0293x; 1.0293x over previous
//
#include <hip/hip_runtime.h>

// MDTA: B=4, C=384, H=W=128, HEADS=8, D=48
#define HW    16384
#define WD    128
#define CCH   384
#define NB    4
#define NHEAD 8
#define DH    48
#define NCHUNK 16  // score partial chunks (pixels per chunk = HW/NCHUNK = 1024)
#define PREPB 889  // prep blocks appended to ln grid (455040 elems / 512)

typedef unsigned short u16;
typedef unsigned int   u32;
typedef __bf16 bf16x8 __attribute__((ext_vector_type(8)));
typedef float  f32x4  __attribute__((ext_vector_type(4)));

__device__ __forceinline__ float bf2f(u16 u){ u32 t=((u32)u)<<16; float f; __builtin_memcpy(&f,&t,4); return f; }
__device__ __forceinline__ u16 f2bf(float f){ u32 x; __builtin_memcpy(&x,&f,4); u32 r=x+0x7fffu+((x>>16)&1u); return (u16)(r>>16); }
__device__ __forceinline__ f32x4 zero4(){ f32x4 z = {0.f,0.f,0.f,0.f}; return z; }

#define GL16(g,l) __builtin_amdgcn_global_load_lds(\
    (const __attribute__((address_space(1))) void*)(g), \
    (__attribute__((address_space(3))) void*)(l), 16, 0, 0)

// ---------------- LayerNorm (-> xn_t [b][p][c]) + weight prep, one launch ----------------
__global__ __launch_bounds__(512, 4) void ln_prep_kernel(
    const float* __restrict__ x, const float* __restrict__ gamma,
    const float* __restrict__ beta, u16* __restrict__ xnt,
    const float* wq_p, const float* wk_p, const float* wv_p,
    const float* bq_p, const float* bk_p, const float* bv_p,
    const float* wq_d, const float* wk_d, const float* wv_d,
    const float* bq_d, const float* bk_d, const float* bv_d,
    u16* Wqkv, float* bias_p, float* wdc, float* bdc)
{
    if (blockIdx.x >= 256) {
        if (blockIdx.y != 0) return;
        int idx = (blockIdx.x - 256)*512 + threadIdx.x;
        const int NW = 3*CCH*CCH;                 // 442368
        if (idx < NW) {
            int m = idx / CCH, c = idx % CCH;
            int w = m / CCH, o = m % CCH;
            const float* src = (w==0)? wq_p : (w==1)? wk_p : wv_p;
            Wqkv[idx] = f2bf(src[o*CCH + c]);
        } else if (idx < NW + 3*CCH) {
            int m = idx - NW; int w = m/CCH, o = m%CCH;
            const float* src = (w==0)? bq_p : (w==1)? bk_p : bv_p;
            bias_p[m] = src[o];
        } else if (idx < NW + 3*CCH + 3*CCH*9) {
            int r = idx - NW - 3*CCH; int m = r/9, k = r%9;
            int w = m/CCH, o = m%CCH;
            const float* src = (w==0)? wq_d : (w==1)? wk_d : wv_d;
            wdc[r] = src[o*9 + k];
        } else if (idx < NW + 3*CCH + 3*CCH*9 + 3*CCH) {
            int m = idx - NW - 3*CCH - 3*CCH*9; int w = m/CCH, o = m%CCH;
            const float* src = (w==0)? bq_d : (w==1)? bk_d : bv_d;
            bdc[m] = src[o];
        }
        return;
    }
    __shared__ __align__(16) char lds[32*392*2 + 512];
    u16  (*tile)[392] = (u16(*)[392])lds;
    f32x4* redS  = (f32x4*)lds;                // overlays tile (temporally disjoint)
    f32x4* redS2 = (f32x4*)(lds + 8192);
    float* mu_s  = (float*)(lds + 32*392*2);
    float* rs_s  = mu_s + 64;
    int b  = blockIdx.y;
    int p0 = blockIdx.x*64;
    int t  = threadIdx.x;
    int tx = t & 15, cg = t >> 4;              // 16 pixel-quads x 32 channel-groups of 12
    const float* xb = x + (size_t)b*CCH*HW + p0 + tx*4;
    f32x4 vals[12];
    f32x4 s = zero4(), s2 = zero4();
    #pragma unroll
    for (int cc = 0; cc < 12; ++cc) {
        f32x4 v = *(const f32x4*)(xb + (size_t)(cg*12+cc)*HW);
        vals[cc] = v;
        s += v; s2 += v*v;
    }
    redS[cg*16+tx] = s; redS2[cg*16+tx] = s2;
    __syncthreads();
    if (t < 64) {
        int q = t >> 2, comp = t & 3;
        const float* rs1 = (const float*)redS;
        const float* rs2 = (const float*)redS2;
        float st = 0.f, st2 = 0.f;
        #pragma unroll
        for (int g2 = 0; g2 < 32; ++g2) {
            st  += rs1[(g2*16+q)*4 + comp];
            st2 += rs2[(g2*16+q)*4 + comp];
        }
        float mu  = st*(1.f/CCH);
        float var = st2*(1.f/CCH) - mu*mu;
        mu_s[t] = mu;
        rs_s[t] = rsqrtf(var + 1e-5f);
    }
    __syncthreads();
    f32x4 mu4, rs4;
    #pragma unroll
    for (int j = 0; j < 4; ++j) { mu4[j] = mu_s[tx*4+j]; rs4[j] = rs_s[tx*4+j]; }
    u32 pk[12][2];
    #pragma unroll
    for (int cc = 0; cc < 12; ++cc) {
        int c = cg*12 + cc;
        float gm = gamma[c], bt = beta[c];
        f32x4 v = (vals[cc] - mu4) * rs4;
        u16 o0 = f2bf(v[0]*gm + bt), o1 = f2bf(v[1]*gm + bt);
        u16 o2 = f2bf(v[2]*gm + bt), o3 = f2bf(v[3]*gm + bt);
        pk[cc][0] = (u32)o0 | ((u32)o1 << 16);
        pk[cc][1] = (u32)o2 | ((u32)o3 << 16);
    }
    u16* xto = xnt + (size_t)b*CCH*HW;
    int half = tx >> 3, txl = tx & 7;
    #pragma unroll
    for (int p2 = 0; p2 < 2; ++p2) {
        if (half == p2) {
            #pragma unroll
            for (int i = 0; i < 4; ++i) {       // pixel within quad
                int row = txl*4 + i;
                #pragma unroll
                for (int j = 0; j < 3; ++j) {   // 4-channel group
                    #define EXTB(cc) ((pk[cc][i>>1] >> (16*(i&1))) & 0xffffu)
                    u32 a0 = EXTB(4*j+0) | (EXTB(4*j+1) << 16);
                    u32 a1 = EXTB(4*j+2) | (EXTB(4*j+3) << 16);
                    #undef EXTB
                    uint2 pr; pr.x = a0; pr.y = a1;
                    *(uint2*)&tile[row][cg*12 + j*4] = pr;
                }
            }
        }
        __syncthreads();
        #pragma unroll
        for (int k = 0; k < 3; ++k) {
            int idx = t + k*512;
            int p = idx / 48, q = idx % 48;
            *(uint4*)(xto + (size_t)(p0 + p2*32 + p)*CCH + q*8) = *(const uint4*)&tile[p][q*8];
        }
        __syncthreads();
    }
}

// ---------------- NT MFMA GEMM: C[m][n] = sum_k A[m][k]*B[n][k]  (K=384) ----------------
// 128x128 tile, BK=64, 8 waves (64x32 each). XCD-aware block swizzle (T1).
// TRANSB=0: single-buffer 32KB, GL16 both operands (r3-proven structure).
// TRANSB=1: B=[k][n] (V in [c][p]). Full dbuf + raw s_barrier + counted vmcnt;
//   B prefetched 2 K-steps ahead in two register sets (stays in flight across barriers).
// EPI 0: +bias, store bf16 direct per-lane (measured faster than LDS shuffle, R15).
// EPI 1: +bias + residual read from xn_t [p][c] via LDS transpose tile, store f32.
template<int EPI, int TRANSB>
__global__ __launch_bounds__(512) void gemm_nt(
    const u16* __restrict__ A, const u16* __restrict__ Bm, void* __restrict__ Cout,
    const float* __restrict__ bias, const u16* __restrict__ xnadd,
    long A_bstride, long B_bstride, long C_bstride)
{
    constexpr int SMBYTES = TRANSB ? 65536 : 32768;
    __shared__ __align__(16) char smraw[SMBYTES];
    u16* smA = (u16*)smraw;                               // TRANSB=1: 2 x 16KB dbuf
    u16* smB = (u16*)(smraw + (TRANSB ? 32768 : 16384));  // TRANSB=1: 2 x 16KB dbuf

    // XCD swizzle: lin -> (lin%8)*(N/8) + lin/8 (bijective when N%8==0)
    int gx = gridDim.x, gy = gridDim.y;
    int Ngrid = gx*gy*gridDim.z;
    int lin = blockIdx.x + gx*(blockIdx.y + gy*blockIdx.z);
    int swz = ((Ngrid & 7) == 0) ? ((lin & 7)*(Ngrid >> 3) + (lin >> 3)) : lin;
    int bx = swz % gx; int rem = swz / gx;
    int by = rem % gy; int b  = rem / gy;
    int m0 = bx*128, n0 = by*128;

    const u16* Ab = A  + (size_t)b*A_bstride;
    const u16* Bb = Bm + (size_t)b*B_bstride;
    int t = threadIdx.x;
    int lane = t & 63, w = t >> 6;
    int wr = w >> 2, wc = w & 3;              // rows wr*64.., cols wc*32..
    int l15 = lane & 15, g = lane >> 4;
    int s7 = l15 & 7;

    int rowA[2], kksA[2];
    #pragma unroll
    for (int r = 0; r < 2; ++r) {
        int e = (r*512 + t)*8;
        rowA[r] = e >> 6;
        int kk  = e & 63;
        kksA[r] = kk ^ ((rowA[r]&7)<<3);      // pre-swizzle source -> linear LDS dest is swizzled
    }
    // TRANSB=1 reg-staging coords: thread owns channels (cB, cB+1) x 8 pixels
    int cB  = (2*t) & 63;                     // even
    int pxg = (2*t) >> 6;                     // 0..15

    f32x4 acc[4][2];
    #pragma unroll
    for (int i=0;i<4;++i) { acc[i][0] = zero4(); acc[i][1] = zero4(); }

#define COMPUTE(sAp, sBp) { \
    const u16* sA_ = (sAp); const u16* sB_ = (sBp); \
    _Pragma("unroll") \
    for (int kh = 0; kh < 2; ++kh) { \
        int u = (kh*4 + g) ^ s7; \
        bf16x8 af[4], bq[2]; \
        _Pragma("unroll") \
        for (int mi=0;mi<4;++mi) { \
            int row = wr*64 + mi*16 + l15; \
            af[mi] = *(const bf16x8*)&sA_[row*64 + u*8]; \
        } \
        _Pragma("unroll") \
        for (int nj=0;nj<2;++nj) { \
            int row = wc*32 + nj*16 + l15; \
            bq[nj] = *(const bf16x8*)&sB_[row*64 + u*8]; \
        } \
        _Pragma("unroll") \
        for (int mi=0;mi<4;++mi) \
            _Pragma("unroll") \
            for (int nj=0;nj<2;++nj) \
                acc[mi][nj] = __builtin_amdgcn_mfma_f32_16x16x32_bf16(af[mi], bq[nj], acc[mi][nj], 0,0,0); \
    } }

#define WRITE_SMB(dst, va, vb) { \
    u16 e0[8], e1[8]; \
    __builtin_memcpy(e0,&(va),16); __builtin_memcpy(e1,&(vb),16); \
    _Pragma("unroll") \
    for (int j=0;j<8;++j) { \
        u32 wv = (u32)e0[j] | ((u32)e1[j]<<16); \
        *(u32*)((dst) + (pxg*8+j)*64 + (cB ^ (j<<3))) = wv; \
    } }

    if (!TRANSB) {
        // ---- r3-proven single-buffer 2-barrier loop ----
        #pragma unroll
        for (int r = 0; r < 2; ++r) {
            GL16(Ab + (size_t)(m0+rowA[r])*CCH + kksA[r], smA + r*4096 + w*512);
            GL16(Bb + (size_t)(n0+rowA[r])*CCH + kksA[r], smB + r*4096 + w*512);
        }
        __syncthreads();
        for (int ks = 0; ks < 6; ++ks) {
            COMPUTE(smA, smB);
            if (ks < 5) {
                __syncthreads();
                int k1 = (ks+1)*64;
                #pragma unroll
                for (int r = 0; r < 2; ++r) {
                    GL16(Ab + (size_t)(m0+rowA[r])*CCH + k1 + kksA[r], smA + r*4096 + w*512);
                    GL16(Bb + (size_t)(n0+rowA[r])*CCH + k1 + kksA[r], smB + r*4096 + w*512);
                }
                __syncthreads();
            }
        }
    } else {
        // ---- pipelined: dbuf + raw barrier + counted vmcnt; B 2-deep in regs ----
        uint4 s0a, s0b, s1a, s1b;
        s0a = *(const uint4*)(Bb + (size_t)cB*HW     + n0 + pxg*8);
        s0b = *(const uint4*)(Bb + (size_t)(cB+1)*HW + n0 + pxg*8);
        #pragma unroll
        for (int r = 0; r < 2; ++r)
            GL16(Ab + (size_t)(m0+rowA[r])*CCH + kksA[r], smA + r*4096 + w*512);
        WRITE_SMB(smB, s0a, s0b);             // compiler auto-waits set0
        s1a = *(const uint4*)(Bb + (size_t)(64+cB)*HW   + n0 + pxg*8);   // B(k1) -> set1
        s1b = *(const uint4*)(Bb + (size_t)(64+cB+1)*HW + n0 + pxg*8);
        asm volatile("s_waitcnt vmcnt(2)" ::: "memory");   // A done; set1 stays in flight
        asm volatile("s_waitcnt lgkmcnt(0)" ::: "memory");
        __builtin_amdgcn_sched_barrier(0);
        __builtin_amdgcn_s_barrier();

        #pragma unroll
        for (int ks = 0; ks < 6; ++ks) {
            int cur = ks & 1, nxt = cur ^ 1;
            if (ks < 5) {                      // A for ks+1 (L2-hot wf_eff)
                int k1 = (ks+1)*64;
                #pragma unroll
                for (int r = 0; r < 2; ++r)
                    GL16(Ab + (size_t)(m0+rowA[r])*CCH + k1 + kksA[r],
                         smA + nxt*8192 + r*4096 + w*512);
            }
            if (ks < 4) {                      // B for ks+2 into the freed set
                int k2 = (ks+2)*64;
                if ((ks & 1) == 0) {
                    s0a = *(const uint4*)(Bb + (size_t)(k2+cB)*HW   + n0 + pxg*8);
                    s0b = *(const uint4*)(Bb + (size_t)(k2+cB+1)*HW + n0 + pxg*8);
                } else {
                    s1a = *(const uint4*)(Bb + (size_t)(k2+cB)*HW   + n0 + pxg*8);
                    s1b = *(const uint4*)(Bb + (size_t)(k2+cB+1)*HW + n0 + pxg*8);
                }
            }
            COMPUTE(smA + cur*8192, smB + cur*8192);
            if (ks < 5) {
                if (((ks+1) & 1) == 0) { WRITE_SMB(smB + nxt*8192, s0a, s0b); }
                else                   { WRITE_SMB(smB + nxt*8192, s1a, s1b); }
                if (ks < 4) asm volatile("s_waitcnt vmcnt(2)" ::: "memory");  // A drained, B(ks+2) in flight
                else        asm volatile("s_waitcnt vmcnt(0)" ::: "memory");
                asm volatile("s_waitcnt lgkmcnt(0)" ::: "memory");
                __builtin_amdgcn_sched_barrier(0);
                __builtin_amdgcn_s_barrier();
            }
        }
    }

    if (EPI == 0) {
        #pragma unroll
        for (int mi=0;mi<4;++mi) {
            #pragma unroll
            for (int r=0;r<4;++r) {
                int grow = m0 + wr*64 + mi*16 + g*4 + r;
                float bv = bias[grow];
                #pragma unroll
                for (int nj=0;nj<2;++nj) {
                    int gcol = n0 + wc*32 + nj*16 + l15;
                    ((u16*)Cout)[(size_t)b*C_bstride + (size_t)grow*HW + gcol] = f2bf(acc[mi][nj][r] + bv);
                }
            }
        }
    } else {
        // LDS-shuffled epilogue + xn_t residual transpose tile.
        float* epi = (float*)smraw;                 // 64 x 132 f32 = 33792 B
        u16*   xt  = (u16*)(smraw + 33792);         // [64 ch][132 px] u16 = 16896 B
        const u16* xtg = xnadd + (size_t)b*CCH*HW;  // xn_t [p][c]
        #pragma unroll
        for (int half = 0; half < 2; ++half) {
            __syncthreads();                  // smraw free (K-loop / prior half done)
            // fill xt: 128 px x 64 ch of this half, transposed to [ch][px]
            #pragma unroll
            for (int q2 = 0; q2 < 2; ++q2) {
                int idx2 = t*2 + q2;          // 0..1023
                int px  = idx2 >> 3;          // 0..127
                int oct = idx2 & 7;           // 8 channel-octets
                int chl = (oct < 4) ? (half*32 + oct*8) : (64 + half*32 + (oct-4)*8);
                uint4 v4 = *(const uint4*)(xtg + (size_t)(n0+px)*CCH + m0 + chl);
                u16 e[8]; __builtin_memcpy(e, &v4, 16);
                int col = oct*8;              // lrow index 0..63
                #pragma unroll
                for (int j = 0; j < 8; ++j)
                    xt[(col+j)*132 + px] = e[j];
            }
            #pragma unroll
            for (int mi2 = 0; mi2 < 2; ++mi2) {
                int mi = half*2 + mi2;
                #pragma unroll
                for (int r = 0; r < 4; ++r) {
                    int lrow = wr*32 + mi2*16 + g*4 + r;
                    int grow = m0 + wr*64 + half*32 + mi2*16 + g*4 + r;
                    float bv = bias[grow];
                    #pragma unroll
                    for (int nj = 0; nj < 2; ++nj)
                        epi[lrow*132 + wc*32 + nj*16 + l15] = acc[mi][nj][r] + bv;
                }
            }
            __syncthreads();
            #pragma unroll
            for (int k = 0; k < 4; ++k) {
                int idx = t + k*512;
                int lrow = idx >> 5, cq = idx & 31;
                int grow = m0 + (lrow>>5)*64 + half*32 + (lrow&31);
                int gcol = n0 + cq*4;
                f32x4 v = *(const f32x4*)&epi[lrow*132 + cq*4];
                uint2 xv = *(const uint2*)&xt[lrow*132 + cq*4];   // 4 px bf16
                v[0] += bf2f((u16)xv.x);        v[1] += bf2f((u16)(xv.x>>16));
                v[2] += bf2f((u16)xv.y);        v[3] += bf2f((u16)(xv.y>>16));
                *(f32x4*)((float*)Cout + (size_t)b*C_bstride + (size_t)grow*HW + gcol) = v;
            }
        }
    }
#undef COMPUTE
#undef WRITE_SMB
}

// ---------------- depthwise 3x3 SAME, bf16 in/out, [b][cpb][p] ----------------
// LDS-staged: GL16 the 18-row halo tile (20 rows incl. pad) once per block;
// compute reads ds_read_b128 + LDS halos; y-boundary rows zeroed in LDS.
__global__ __launch_bounds__(256) void dw_kernel(
    const u16* __restrict__ in, u16* __restrict__ out,
    const float* __restrict__ wd, const float* __restrict__ bd, int cpb)
{
    __shared__ __align__(16) u16 srow[20*WD];     // 20 rows x 128 px bf16 = 5120 B
    int b  = blockIdx.z;
    int c  = blockIdx.y;
    int yt = blockIdx.x;                          // 0..7, 16 output rows each
    int t  = threadIdx.x;
    int lane = t & 63, w = t >> 6;
    int y0 = yt*16;
    const u16* plane = in + (size_t)b*cpb*HW + (size_t)c*HW;
    // stage rows r=0..15 (image y0-1+r, clamped), wave w -> LDS rows w*4..w*4+3
    {
        int r  = t >> 4;                          // 0..15
        int sg = t & 15;
        int yy = y0 - 1 + r;
        yy = yy < 0 ? 0 : (yy >= WD ? WD-1 : yy);
        GL16(plane + (size_t)yy*WD + sg*8, srow + w*4*WD);
    }
    if (t < 64) {                                 // rows 16..19 (17 used; 18,19 pad)
        int r  = 16 + (t >> 4);
        int sg = t & 15;
        int yy = y0 - 1 + r;
        yy = yy < 0 ? 0 : (yy >= WD ? WD-1 : yy);
        GL16(plane + (size_t)yy*WD + sg*8, srow + 16*WD);
    }
    __syncthreads();                              // drains vmcnt: tile resident
    if (yt == 0 && t < 16)
        ((uint4*)srow)[t] = make_uint4(0,0,0,0);              // image row -1 -> 0
    if (yt == (WD/16 - 1) && t < 16)
        *((uint4*)(srow + 17*WD) + t) = make_uint4(0,0,0,0);  // image row 128 -> 0
    __syncthreads();

    int ty = t >> 4, tx = t & 15;
    int y  = y0 + ty;
    int x0 = tx*8;
    float w9[9];
    #pragma unroll
    for (int i=0;i<9;++i) w9[i] = wd[c*9+i];
    float bv = bd[c];
    float rows[3][10];
    #pragma unroll
    for (int dy=0; dy<3; ++dy) {
        const u16* rp = srow + (ty+dy)*WD;
        rows[dy][0] = (tx==0) ? 0.f : bf2f(rp[x0-1]);
        uint4 v = *(const uint4*)(rp + x0);       // ds_read_b128, conflict-free
        u16 e[8]; __builtin_memcpy(e,&v,16);
        #pragma unroll
        for (int i=0;i<8;++i) rows[dy][1+i] = bf2f(e[i]);
        rows[dy][9] = (tx==15) ? 0.f : bf2f(rp[x0+8]);
    }
    u16 ovals[8];
    #pragma unroll
    for (int xo=0; xo<8; ++xo) {
        float a = bv;
        #pragma unroll
        for (int dy=0;dy<3;++dy)
            #pragma unroll
            for (int dx=0;dx<3;++dx)
                a += rows[dy][xo+dx] * w9[dy*3+dx];
        ovals[xo] = f2bf(a);
    }
    uint4 ov; __builtin_memcpy(&ov, ovals, 16);
    *(uint4*)(out + (size_t)b*cpb*HW + (size_t)c*HW + y*WD + x0) = ov;
}

// ---------------- scores partials: 4 waves split the pixel chunk, LDS cross-wave reduce ----------------
__global__ __launch_bounds__(256) void scores_kernel(const u16* __restrict__ Kp,
                                                     const u16* __restrict__ Qp,
                                                     float* __restrict__ S_part, int cpb)
{
    __shared__ float red[3*DH*DH];            // waves 1..3 partial dumps (27648 B)
    int pc = blockIdx.x;                      // 0..NCHUNK-1 pixel chunks
    int h  = blockIdx.y;
    int b  = blockIdx.z;
    int t  = threadIdx.x;
    int lane = t & 63, wv = t >> 6;
    int l15 = lane & 15, g = lane >> 4;
    const u16* Kb = Kp + (size_t)b*cpb*HW + (size_t)(h*DH)*HW;
    const u16* Qb = Qp + (size_t)b*cpb*HW + (size_t)(h*DH)*HW;
    int p0 = pc*(HW/NCHUNK) + wv*(HW/NCHUNK/4);    // 256 px per wave
    f32x4 acc[3][3];
    #pragma unroll
    for (int i=0;i<3;++i)
        #pragma unroll
        for (int j=0;j<3;++j) acc[i][j] = zero4();
    #pragma unroll
    for (int kk=0; kk<(HW/NCHUNK/4)/32; ++kk) {    // 8 iters
        int p = p0 + kk*32 + g*8;
        bf16x8 af[3], bq[3];
        #pragma unroll
        for (int it=0; it<3; ++it)
            af[it] = *(const bf16x8*)(Kb + (size_t)(it*16 + l15)*HW + p);
        #pragma unroll
        for (int jt=0; jt<3; ++jt)
            bq[jt] = *(const bf16x8*)(Qb + (size_t)(jt*16 + l15)*HW + p);
        #pragma unroll
        for (int it=0;it<3;++it)
            #pragma unroll
            for (int jt=0;jt<3;++jt)
                acc[it][jt] = __builtin_amdgcn_mfma_f32_16x16x32_bf16(af[it], bq[jt], acc[it][jt], 0,0,0);
    }
    if (wv > 0) {
        float* dst = red + (wv-1)*(DH*DH) + lane*36;
        #pragma unroll
        for (int it=0;it<3;++it)
            #pragma unroll
            for (int jt=0;jt<3;++jt)
                *(f32x4*)(dst + (it*3+jt)*4) = acc[it][jt];
    }
    __syncthreads();
    if (wv == 0) {
        #pragma unroll
        for (int it=0;it<3;++it)
            #pragma unroll
            for (int jt=0;jt<3;++jt) {
                #pragma unroll
                for (int w2=0; w2<3; ++w2)
                    acc[it][jt] += *(const f32x4*)(red + w2*(DH*DH) + lane*36 + (it*3+jt)*4);
            }
        float* Sp = S_part + ((size_t)pc*32 + b*NHEAD + h)*(DH*DH);
        #pragma unroll
        for (int it=0;it<3;++it)
            #pragma unroll
            for (int jt=0;jt<3;++jt)
                #pragma unroll
                for (int r=0;r<4;++r) {
                    int i = it*16 + g*4 + r;
                    int j = jt*16 + l15;
                    Sp[i*DH + j] = acc[it][jt][r];
                }
    }
}

// ---------------- fold (absorbs softmax): reduce partials + softmax + fold into wf ----------------
// wf_eff[b][o][n*48+i] = sum_j wf[o][n*48+j]*softmax(S)[b,n,i,j]
__global__ __launch_bounds__(256) void fold_kernel(const float* __restrict__ wf,
                                                   const float* __restrict__ S_part,
                                                   const float* __restrict__ alpha,
                                                   u16* __restrict__ wf_eff)
{
    __shared__ float softl[DH*DH];            // 9216 B
    __shared__ float wfl[16*DH];              // 3072 B
    int ob = blockIdx.x, h = blockIdx.y, b = blockIdx.z;
    int t = threadIdx.x;
    int bh = b*NHEAD + h;
    float ia = 1.f / alpha[h];
    for (int e = t; e < DH*DH; e += 256) {
        float s = 0.f;
        #pragma unroll
        for (int pc=0; pc<NCHUNK; ++pc) s += S_part[((size_t)pc*32 + bh)*(DH*DH) + e];
        softl[e] = s * ia;
    }
    for (int k = t; k < 16*DH; k += 256) {
        int ol = k / DH, j = k % DH;
        wfl[k] = wf[(size_t)(ob*16 + ol)*CCH + h*DH + j];
    }
    __syncthreads();
    if (t < DH) {
        float m = -1e30f;
        for (int j=0;j<DH;++j) m = fmaxf(m, softl[t*DH+j]);
        float sum = 0.f;
        for (int j=0;j<DH;++j) sum += __expf(softl[t*DH+j]-m);
        float inv = 1.f/sum;
        for (int j=0;j<DH;++j)
            softl[t*DH+j] = __expf(softl[t*DH+j]-m)*inv;
    }
    __syncthreads();
    #pragma unroll
    for (int r = 0; r < 3; ++r) {
        int out = r*256 + t;                  // 0..767
        int ol = out / DH, i = out % DH;
        const f32x4* wr_ = (const f32x4*)&wfl[ol*DH];
        const f32x4* sr  = (const f32x4*)&softl[i*DH];
        f32x4 a4 = zero4();
        #pragma unroll
        for (int j = 0; j < 12; ++j) a4 += wr_[j]*sr[j];
        float a = a4[0]+a4[1]+a4[2]+a4[3];
        wf_eff[((size_t)b*CCH + ob*16 + ol)*CCH + h*DH + i] = f2bf(a);
    }
}

extern "C" void kernel_launch(void* const* d_in, const int* in_sizes, int n_in,
                              void* d_out, int out_size, void* d_ws, size_t ws_size,
                              hipStream_t stream)
{
    const float* x    = (const float*)d_in[0];
    const float* ln_g = (const float*)d_in[1];
    const float* ln_b = (const float*)d_in[2];
    const float* wq_p = (const float*)d_in[3];
    const float* bq_p = (const float*)d_in[4];
    const float* wq_d = (const float*)d_in[5];
    const float* bq_d = (const float*)d_in[6];
    const float* wk_p = (const float*)d_in[7];
    const float* bk_p = (const float*)d_in[8];
    const float* wk_d = (const float*)d_in[9];
    const float* bk_d = (const float*)d_in[10];
    const float* wv_p = (const float*)d_in[11];
    const float* bv_p = (const float*)d_in[12];
    const float* wv_d = (const float*)d_in[13];
    const float* bv_d = (const float*)d_in[14];
    const float* alpha= (const float*)d_in[15];
    const float* wf   = (const float*)d_in[16];
    const float* bf_  = (const float*)d_in[17];

    char* ws = (char*)d_ws;
    size_t off = 0;
    auto alloc = [&](size_t bytes)->char* { char* p = ws + off; off += (bytes + 255) & ~(size_t)255; return p; };
    const size_t BIG  = (size_t)NB*CCH*HW*2;       // 50.3 MB bf16 [b][384][16384]
    const size_t BIG3 = 3*BIG;                     // 151 MB   [b][1152][16384]
    const size_t SMALLS = (size_t)3*CCH*CCH*2 + 3*CCH*4 + 3*CCH*9*4 + 3*CCH*4
                        + (size_t)NCHUNK*32*DH*DH*4 + (size_t)32*DH*DH*4
                        + (size_t)NB*CCH*CCH*2 + 16*256;
    const size_t NEED_FUSED = BIG + 2*BIG3 + SMALLS;
    const bool fused = (ws_size >= NEED_FUSED);
    const long BStr = (long)CCH*HW;

    if (fused) {
        u16* xn_t   = (u16*)alloc(BIG);
        u16* pwQKV  = (u16*)alloc(BIG3);
        u16* dwQKV  = (u16*)alloc(BIG3);
        u16*   Wqkv   = (u16*)  alloc((size_t)3*CCH*CCH*2);
        float* bias_p = (float*)alloc((size_t)3*CCH*4);
        float* wdc    = (float*)alloc((size_t)3*CCH*9*4);
        float* bdc    = (float*)alloc((size_t)3*CCH*4);
        float* S_part = (float*)alloc((size_t)NCHUNK*32*DH*DH*4);
        float* soft   = (float*)alloc((size_t)32*DH*DH*4);
        u16*   wf_eff = (u16*)  alloc((size_t)NB*CCH*CCH*2);
        (void)soft;

        ln_prep_kernel<<<dim3(256+PREPB,NB), 512, 0, stream>>>(
            x, ln_g, ln_b, xn_t,
            wq_p,wk_p,wv_p, bq_p,bk_p,bv_p, wq_d,wk_d,wv_d, bq_d,bk_d,bv_d,
            Wqkv, bias_p, wdc, bdc);
        // fused QKV pointwise: M=1152
        gemm_nt<0,0><<<dim3(9,128,NB), 512, 0, stream>>>(Wqkv, xn_t, pwQKV, bias_p, nullptr,
                                                         0, BStr, (long)3*CCH*HW);
        dw_kernel<<<dim3(8,3*CCH,NB), 256, 0, stream>>>(pwQKV, dwQKV, wdc, bdc, 3*CCH);
        scores_kernel<<<dim3(NCHUNK,NHEAD,NB), 256, 0, stream>>>(dwQKV + (size_t)CCH*HW, // K
                                                                 dwQKV,                  // Q
                                                                 S_part, 3*CCH);
        fold_kernel<<<dim3(CCH/16, NHEAD, NB), 256, 0, stream>>>(wf, S_part, alpha, wf_eff);
        // final: x_cap = wf_eff x V + bf + xn(from xn_t) ; V consumed directly in [c][p]
        gemm_nt<1,1><<<dim3(3,128,NB), 512, 0, stream>>>(wf_eff, dwQKV + (size_t)2*CCH*HW,
                                                         d_out, bf_, xn_t,
                                                         (long)CCH*CCH, (long)3*CCH*HW, BStr);
    } else {
        u16* xn_t  = (u16*)alloc(BIG);
        u16* pwA   = (u16*)alloc(BIG);
        u16* dwQ   = (u16*)alloc(BIG);
        u16* dwK   = (u16*)alloc(BIG);
        u16*   Wqkv   = (u16*)  alloc((size_t)3*CCH*CCH*2);
        float* bias_p = (float*)alloc((size_t)3*CCH*4);
        float* wdc    = (float*)alloc((size_t)3*CCH*9*4);
        float* bdc    = (float*)alloc((size_t)3*CCH*4);
        float* S_part = (float*)alloc((size_t)NCHUNK*32*DH*DH*4);
        float* soft   = (float*)alloc((size_t)32*DH*DH*4);
        u16*   wf_eff = (u16*)  alloc((size_t)NB*CCH*CCH*2);
        if (off > ws_size) return;
        (void)soft;
        u16* dwV = dwQ;                        // dwQ dead after scores

        ln_prep_kernel<<<dim3(256+PREPB,NB), 512, 0, stream>>>(
            x, ln_g, ln_b, xn_t,
            wq_p,wk_p,wv_p, bq_p,bk_p,bv_p, wq_d,wk_d,wv_d, bq_d,bk_d,bv_d,
            Wqkv, bias_p, wdc, bdc);
        gemm_nt<0,0><<<dim3(3,128,NB), 512, 0, stream>>>(Wqkv,           xn_t, pwA, bias_p,       nullptr, 0, BStr, BStr);
        dw_kernel<<<dim3(8,CCH,NB), 256, 0, stream>>>(pwA, dwQ, wdc,         bdc,       CCH);
        gemm_nt<0,0><<<dim3(3,128,NB), 512, 0, stream>>>(Wqkv + CCH*CCH, xn_t, pwA, bias_p + CCH, nullptr, 0, BStr, BStr);
        dw_kernel<<<dim3(8,CCH,NB), 256, 0, stream>>>(pwA, dwK, wdc + CCH*9, bdc + CCH, CCH);
        scores_kernel<<<dim3(NCHUNK,NHEAD,NB), 256, 0, stream>>>(dwK, dwQ, S_part, CCH);
        fold_kernel<<<dim3(CCH/16, NHEAD, NB), 256, 0, stream>>>(wf, S_part, alpha, wf_eff);
        gemm_nt<0,0><<<dim3(3,128,NB), 512, 0, stream>>>(Wqkv + 2*CCH*CCH, xn_t, pwA, bias_p + 2*CCH, nullptr, 0, BStr, BStr);
        dw_kernel<<<dim3(8,CCH,NB), 256, 0, stream>>>(pwA, dwV, wdc + 2*CCH*9, bdc + 2*CCH, CCH);
        gemm_nt<1,1><<<dim3(3,128,NB), 512, 0, stream>>>(wf_eff, dwV, d_out, bf_, xn_t,
                                                         (long)CCH*CCH, BStr, BStr);
    }
}